// Round 7
// baseline (133.820 us; speedup 1.0000x reference)
//
#include <hip/hip_runtime.h>
#include <math.h>

#define TPB 256
#define MTPB 512       // match / topk block size
#define CE_BLOCKS 2048 // k_ce grid (8 blocks/CU on 256 CUs)
#define SEGS 4         // priors-segments per batch row for match kernels

__device__ __forceinline__ float sl1(float x) {
    float a = fabsf(x);
    return a < 1.f ? 0.5f * a * a : a - 0.5f;
}

// ---------------------------------------------------------------------------
// K1a: segment IoU pass. Grid = B*SEGS blocks (fills all 256 CUs).
// Block (b,s): per-prior best object -> packed byte (obj | lt05<<4 | gt04<<5)
// (pass-2 only needs the threshold bits, not the float IoU), and per-object
// best prior within the segment -> segv/segp. Also zeroes K3's ticket.
// ---------------------------------------------------------------------------
template<int NOBJ>
__global__ __launch_bounds__(MTPB)
void k_match_iou(const float* __restrict__ boxes, const float* __restrict__ priors,
                 int P, unsigned char* __restrict__ obj_pack,
                 float* __restrict__ segv, int* __restrict__ segp,
                 unsigned* __restrict__ ticket)
{
    const int bs = blockIdx.x;
    const int b = bs >> 2;               // SEGS == 4
    const int s = bs & 3;
    const int tid = threadIdx.x;
    const int NW = MTPB / 64;            // 8 waves

    if (bs == 0 && tid == 0) *ticket = 0u;

    __shared__ float redv[NOBJ * (MTPB / 64)];
    __shared__ int   redp[NOBJ * (MTPB / 64)];

    const int seglen = (P + SEGS - 1) / SEGS;
    const int p0 = s * seglen;
    const int p1 = min(p0 + seglen, P);

    // box data in registers (unrolled o -> static indexing, uniform loads)
    float bx1[NOBJ], by1[NOBJ], bx2[NOBJ], by2[NOBJ], bar[NOBJ];
#pragma unroll
    for (int o = 0; o < NOBJ; o++) {
        const float4 bx = ((const float4*)boxes)[(size_t)b * NOBJ + o];
        bx1[o] = bx.x; by1[o] = bx.y;
        bx2[o] = bx.x + bx.z; by2[o] = bx.y + bx.w;
        bar[o] = (bx2[o] - bx1[o]) * (by2[o] - by1[o]);
    }

    float bestv[NOBJ];
    int bestp[NOBJ];
#pragma unroll
    for (int o = 0; o < NOBJ; o++) { bestv[o] = -1.f; bestp[o] = 0x7fffffff; }

    for (int p = p0 + tid; p < p1; p += MTPB) {
        float4 pr = ((const float4*)priors)[p];
        float hx = pr.z * 0.5f, hy = pr.w * 0.5f;
        float px1 = pr.x - hx, py1 = pr.y - hy;
        float px2 = pr.x + hx, py2 = pr.y + hy;
        float parea = (px2 - px1) * (py2 - py1);
        float bv = -1.f; int bo = 0;
#pragma unroll
        for (int o = 0; o < NOBJ; o++) {
            float ltx = fmaxf(bx1[o], px1);
            float lty = fmaxf(by1[o], py1);
            float rbx = fminf(bx2[o], px2);
            float rby = fminf(by2[o], py2);
            float w = rbx - ltx; w = w > 0.f ? w : 0.f;
            float h = rby - lty; h = h > 0.f ? h : 0.f;
            float inter = w * h;
            float iou = __fdividef(inter, bar[o] + parea - inter);
            if (iou > bv) { bv = iou; bo = o; }            // first-max (strict >)
            if (iou > bestv[o]) { bestv[o] = iou; bestp[o] = p; }
        }
        // exact same float compares the reference applies to ovl
        unsigned char pk = (unsigned char)bo
                         | (bv < 0.5f ? 0x10 : 0)
                         | (bv > 0.4f ? 0x20 : 0);
        obj_pack[(size_t)b * P + p] = pk;
    }

    // per-object argmax within segment: wave reduce, then cross-wave
#pragma unroll
    for (int o = 0; o < NOBJ; o++) {
        float v = bestv[o]; int pp = bestp[o];
#pragma unroll
        for (int d = 1; d < 64; d <<= 1) {
            float v2 = __shfl_xor(v, d);
            int   q2 = __shfl_xor(pp, d);
            if (v2 > v || (v2 == v && q2 < pp)) { v = v2; pp = q2; }
        }
        if ((tid & 63) == 0) {
            redv[o * NW + (tid >> 6)] = v;
            redp[o * NW + (tid >> 6)] = pp;
        }
    }
    __syncthreads();

    if (tid < NOBJ) {
        float v = -2.f; int pp = 0x7fffffff;
        for (int w = 0; w < NW; w++) {
            float v2 = redv[tid * NW + w];
            int   q2 = redp[tid * NW + w];
            if (v2 > v || (v2 == v && q2 < pp)) { v = v2; pp = q2; }
        }
        segv[((size_t)b * NOBJ + tid) * SEGS + s] = v;
        segp[((size_t)b * NOBJ + tid) * SEGS + s] = pp;
    }
}

// ---------------------------------------------------------------------------
// K1b: finalize match. Grid = B*SEGS blocks. Every block replicates the tiny
// per-object merge over segments, then does pass-2 on its segment with the
// forced assignment applied INLINE (p compared against the 16 forced priors,
// ascending i -> last-wins, matching scatter semantics).
// Outputs: meta, n_pos_seg[b*SEGS+s], loc_seg[b*SEGS+s].
// ---------------------------------------------------------------------------
template<int NOBJ>
__global__ __launch_bounds__(MTPB)
void k_match_fin(const float* __restrict__ boxes, const int* __restrict__ labels,
                 const float* __restrict__ priors, const float* __restrict__ plocs,
                 const unsigned char* __restrict__ obj_pack,
                 const float* __restrict__ segv, const int* __restrict__ segp,
                 int P, unsigned* __restrict__ meta,
                 int* __restrict__ n_pos_seg, float* __restrict__ loc_seg)
{
    const int bs = blockIdx.x;
    const int b = bs >> 2;
    const int s = bs & 3;
    const int tid = threadIdx.x;

    __shared__ float sbox2[4 * NOBJ];
    __shared__ int s_lab[NOBJ];
    __shared__ int pf[NOBJ];
    __shared__ int s_cnt;
    __shared__ float s_lsum;

    if (tid < NOBJ) {
        const float4 bx = ((const float4*)boxes)[(size_t)b * NOBJ + tid];
        float x1 = bx.x, y1 = bx.y, x2 = bx.x + bx.z, y2 = bx.y + bx.w;
        sbox2[0 * NOBJ + tid] = (x1 + x2) * 0.5f;   // cx
        sbox2[1 * NOBJ + tid] = (y1 + y2) * 0.5f;   // cy
        sbox2[2 * NOBJ + tid] = x2 - x1;            // w
        sbox2[3 * NOBJ + tid] = y2 - y1;            // h
        s_lab[tid] = labels[b * NOBJ + tid];
        // merge per-object best over segments (strict >, tie -> smaller idx)
        float v = -2.f; int pp = 0x7fffffff;
#pragma unroll
        for (int ss = 0; ss < SEGS; ss++) {
            float v2 = segv[((size_t)b * NOBJ + tid) * SEGS + ss];
            int   q2 = segp[((size_t)b * NOBJ + tid) * SEGS + ss];
            if (v2 > v || (v2 == v && q2 < pp)) { v = v2; pp = q2; }
        }
        pf[tid] = pp;
        if (tid == 0) { s_cnt = 0; s_lsum = 0.f; }
    }
    __syncthreads();

    const int seglen = (P + SEGS - 1) / SEGS;
    const int p0 = s * seglen;
    const int p1 = min(p0 + seglen, P);

    int cnt = 0;
    float lsum = 0.f;
    for (int p = p0 + tid; p < p1; p += MTPB) {
        unsigned pk = obj_pack[(size_t)b * P + p];
        int o = (int)(pk & 15u);
        bool lt05 = (pk & 0x10u) != 0;
        bool gt04 = (pk & 0x20u) != 0;
        // inline forced assignment (last-wins over i); forced -> ovl = 1.0
        int fo = -1;
#pragma unroll
        for (int i = 0; i < NOBJ; i++) if (pf[i] == p) fo = i;
        if (fo >= 0) { o = fo; lt05 = false; gt04 = true; }

        int lab = lt05 ? 0 : s_lab[o];
        bool ign = gt04 && lt05;
        bool pos = (lab > 0) && !ign;
        meta[(size_t)b * P + p] = (unsigned)lab | (pos ? 256u : 0u) | (ign ? 512u : 0u);
        if (pos) {
            cnt++;
            float4 pr = ((const float4*)priors)[p];
            float cx = sbox2[0 * NOBJ + o], cy = sbox2[1 * NOBJ + o];
            float bw = sbox2[2 * NOBJ + o], bh = sbox2[3 * NOBJ + o];
            float g0 = (cx - pr.x) / (pr.z / 10.0f);
            float g1 = (cy - pr.y) / (pr.w / 10.0f);
            float g2 = __logf(fabsf(bw / pr.z)) * 5.0f;
            float g3 = __logf(fabsf(bh / pr.w)) * 5.0f;
            float4 pl = ((const float4*)plocs)[(size_t)b * P + p];
            lsum += sl1(pl.x - g0) + sl1(pl.y - g1) + sl1(pl.z - g2) + sl1(pl.w - g3);
        }
    }
#pragma unroll
    for (int d = 1; d < 64; d <<= 1) {
        lsum += __shfl_xor(lsum, d);
        cnt  += __shfl_xor(cnt, d);
    }
    if ((tid & 63) == 0) {
        atomicAdd(&s_cnt, cnt);
        atomicAdd(&s_lsum, lsum);
    }
    __syncthreads();
    if (tid == 0) {
        n_pos_seg[bs] = s_cnt;
        loc_seg[bs] = s_lsum;
    }
}

// ---------------------------------------------------------------------------
// K2 fast path (C == 91), software-pipelined: each wave register-prefetches
// the NEXT 4-row quad (91 float4, 16B-aligned) while computing the current
// quad from a double-buffered private LDS slot. L3/HBM latency hides under
// the logsumexp of the current quad. Wave-coherent LDS: no __syncthreads.
// ---------------------------------------------------------------------------
__global__ __launch_bounds__(TPB)
void k_ce91(const float* __restrict__ scores, const unsigned* __restrict__ meta,
            int BP, float* __restrict__ ce_neg, float* __restrict__ pos_blk)
{
    __shared__ __align__(16) float sf[4][2][364];  // 4 waves x 2 bufs x 91 float4
    __shared__ float sp[4];

    const int tid = threadIdx.x;
    const int wid = tid >> 6;
    const int lane = tid & 63;
    const int g = (tid >> 4) & 3;        // group within wave
    const int l = tid & 15;

    const int nquads = BP >> 2;          // BP divisible by 4
    const int gw = gridDim.x * (TPB / 64);
    const float4* src = (const float4*)scores;

    float psum = 0.f;

    int q = blockIdx.x * (TPB / 64) + wid;
    bool have = q < nquads;
    float4 ra = make_float4(0.f, 0.f, 0.f, 0.f);
    float4 rb = make_float4(0.f, 0.f, 0.f, 0.f);
    unsigned mt = 0u;
    if (have) {
        ra = src[(size_t)q * 91 + lane];
        if (lane < 27) rb = src[(size_t)q * 91 + 64 + lane];
        if (l == 0) mt = meta[(q << 2) + g];
    }
    int buf = 0;

    while (have) {
        // stage current quad into this wave's LDS buffer
        float* wl = &sf[wid][buf][0];
        ((float4*)wl)[lane] = ra;
        if (lane < 27) ((float4*)wl)[64 + lane] = rb;
        const unsigned mt_cur = mt;
        const int q_cur = q;

        // issue next quad's loads (latency hidden under compute below)
        q += gw;
        have = q < nquads;
        if (have) {
            ra = src[(size_t)q * 91 + lane];
            if (lane < 27) rb = src[(size_t)q * 91 + 64 + lane];
            if (l == 0) mt = meta[(q << 2) + g];
        }

        // per-row logsumexp from LDS (wave-coherent; compiler emits lgkmcnt)
        const float* rowp = wl + g * 91;
        float v[6];
        float m = -INFINITY;
#pragma unroll
        for (int j = 0; j < 6; j++) {
            int idx = l + (j << 4);
            v[j] = (idx < 91) ? rowp[idx] : -INFINITY;
            m = fmaxf(m, v[j]);
        }
#pragma unroll
        for (int d = 1; d < 16; d <<= 1) m = fmaxf(m, __shfl_xor(m, d));

        float se = 0.f;
#pragma unroll
        for (int j = 0; j < 6; j++) se += __expf(v[j] - m);
#pragma unroll
        for (int d = 1; d < 16; d <<= 1) se += __shfl_xor(se, d);

        if (l == 0) {
            int lab = (int)(mt_cur & 255u);
            float sv = rowp[lab];
            float ce = __logf(se) + m - sv;
            bool pos = (mt_cur >> 8) & 1u;
            bool ign = (mt_cur >> 9) & 1u;
            ce_neg[(q_cur << 2) + g] = (pos || ign) ? 0.f : ce;
            if (pos) psum += ce;
        }
        buf ^= 1;
    }

#pragma unroll
    for (int d = 1; d < 64; d <<= 1) psum += __shfl_xor(psum, d);
    if ((tid & 63) == 0) sp[tid >> 6] = psum;
    __syncthreads();
    if (tid == 0) pos_blk[blockIdx.x] = sp[0] + sp[1] + sp[2] + sp[3];
}

// ---------------------------------------------------------------------------
// K2 generic fallback (C != 91): direct global->register, as R4/R5.
// ---------------------------------------------------------------------------
__global__ __launch_bounds__(TPB)
void k_ce(const float* __restrict__ scores, const unsigned* __restrict__ meta,
          int BP, int C, float* __restrict__ ce_neg, float* __restrict__ pos_blk)
{
    const int tid = threadIdx.x;
    const int g = tid >> 4;
    const int wg = (tid >> 4) & 3;
    const int l = tid & 15;
    const int tiles = BP >> 4;

    float psum = 0.f;

    for (int t = blockIdx.x; t < tiles; t += gridDim.x) {
        const int row = (t << 4) + g;
        const unsigned mt = meta[row];
        const float* s = scores + (size_t)row * C;

        float v[6];
        float m = -INFINITY;
#pragma unroll
        for (int j = 0; j < 6; j++) {
            int idx = l + (j << 4);
            v[j] = (idx < C) ? s[idx] : -INFINITY;
            m = fmaxf(m, v[j]);
        }
#pragma unroll
        for (int d = 1; d < 16; d <<= 1) m = fmaxf(m, __shfl_xor(m, d));

        float se = 0.f;
#pragma unroll
        for (int j = 0; j < 6; j++) se += __expf(v[j] - m);
#pragma unroll
        for (int d = 1; d < 16; d <<= 1) se += __shfl_xor(se, d);

        const int lab = (int)(mt & 255u);
        float pick = v[0];
#pragma unroll
        for (int j = 1; j < 6; j++) pick = ((lab >> 4) == j) ? v[j] : pick;
        float sv = __shfl(pick, (wg << 4) | (lab & 15));

        if (l == 0) {
            float ce = __logf(se) + m - sv;
            bool pos = (mt >> 8) & 1u;
            bool ign = (mt >> 9) & 1u;
            ce_neg[row] = (pos || ign) ? 0.f : ce;
            if (pos) psum += ce;
        }
    }

#pragma unroll
    for (int d = 1; d < 64; d <<= 1) psum += __shfl_xor(psum, d);
    __shared__ float sp[4];
    if ((tid & 63) == 0) sp[tid >> 6] = psum;
    __syncthreads();
    if (tid == 0) pos_blk[blockIdx.x] = sp[0] + sp[1] + sp[2] + sp[3];
}

// ---------------------------------------------------------------------------
// K3: per-row exact radix-select (4x8-bit, msb first) for sum of top-k of
// ce_neg (k = 3*n_pos), fused with the final combine in the last-arriving
// block. Row register-cached; pass 1 uses ballot/leader wave-aggregation.
// ---------------------------------------------------------------------------
template<int ITEMS>
__global__ __launch_bounds__(MTPB)
void k_topk_final(const float* __restrict__ ce_neg, const int* __restrict__ n_pos_seg,
                  const float* __restrict__ loc_seg, const float* __restrict__ pos_blk,
                  int nposblk, int P, int B,
                  float* __restrict__ hard, unsigned* __restrict__ ticket,
                  float* __restrict__ out)
{
    const int b = blockIdx.x;
    const int tid = threadIdx.x;
    const float* row = ce_neg + (size_t)b * P;
    __shared__ unsigned cnt[256];
    __shared__ float sm[256];
    __shared__ float s_sumhigh;
    __shared__ unsigned s_pref;
    __shared__ int s_krem;
    __shared__ bool s_last;

    int k = 0;
#pragma unroll
    for (int s = 0; s < SEGS; s++) k += n_pos_seg[b * SEGS + s];
    k *= 3;
    if (k > P) k = P;

    // register-cache the row (static indexing only)
    float vals[ITEMS];
#pragma unroll
    for (int i = 0; i < ITEMS; i++) {
        int p = tid + i * MTPB;
        vals[i] = (p < P) ? row[p] : 0.f;
    }

    float hard_b = 0.f;
    if (k > 0) {
        if (tid == 0) { s_sumhigh = 0.f; s_pref = 0u; s_krem = k; }

        for (int shift = 24; shift >= 0; shift -= 8) {
            if (tid < 256) { cnt[tid] = 0u; sm[tid] = 0.f; }
            __syncthreads();

            if (shift == 24) {
                // ballot/leader aggregation (few distinct exponent bins)
#pragma unroll
                for (int i = 0; i < ITEMS; i++) {
                    int p = tid + i * MTPB;
                    float vv = vals[i];
                    unsigned bin = __float_as_uint(vv) >> 24;
                    bool done = (p >= P);
                    while (__any(!done)) {
                        unsigned long long act = __ballot(!done);
                        int leader = (int)__ffsll(act) - 1;
                        unsigned lb = (unsigned)__shfl((int)bin, leader);
                        bool mine = (!done) && (bin == lb);
                        float contrib = mine ? vv : 0.f;
#pragma unroll
                        for (int d = 1; d < 64; d <<= 1)
                            contrib += __shfl_xor(contrib, d);
                        unsigned long long grp = __ballot(mine);
                        if ((tid & 63) == leader) {
                            atomicAdd(&cnt[lb], (unsigned)__popcll(grp));
                            atomicAdd(&sm[lb], contrib);
                        }
                        done = done || mine;
                    }
                }
            } else {
                unsigned pref = s_pref;
                const int high = shift + 8;
#pragma unroll
                for (int i = 0; i < ITEMS; i++) {
                    int p = tid + i * MTPB;
                    float vv = vals[i];
                    unsigned u = __float_as_uint(vv);
                    if (p < P && ((u >> high) == (pref >> high))) {
                        unsigned bin = (u >> shift) & 255u;
                        atomicAdd(&cnt[bin], 1u);
                        atomicAdd(&sm[bin], vv);
                    }
                }
            }
            __syncthreads();
            if (tid == 0) {
                int krem = s_krem;
                float sh = s_sumhigh;
                unsigned p2 = s_pref;
                for (int bin = 255; bin >= 0; --bin) {
                    if ((int)cnt[bin] < krem) { krem -= (int)cnt[bin]; sh += sm[bin]; }
                    else { p2 |= ((unsigned)bin) << shift; break; }
                }
                s_krem = krem; s_sumhigh = sh; s_pref = p2;
            }
            __syncthreads();
        }
        if (tid == 0) {
            float t = __uint_as_float(s_pref);
            hard_b = s_sumhigh + (float)s_krem * t;
        }
    }

    // ---- publish + ticket (device-scope) ----------------------------------
    if (tid == 0) {
        atomicExch(&hard[b], hard_b);      // coherent publish
        __threadfence();                    // order publish before ticket
        unsigned old = atomicAdd(ticket, 1u);
        s_last = (old == (unsigned)(gridDim.x - 1));
    }
    __syncthreads();
    if (!s_last) return;

    // ---- fused final combine (last block only) -----------------------------
    __threadfence();
    float hd = (tid < B) ? atomicAdd(&hard[tid], 0.f) : 0.f;  // coherent read
    float lc = 0.f; int np = 0;
    for (int i = tid; i < B * SEGS; i += MTPB) {
        lc += loc_seg[i];
        np += n_pos_seg[i];
    }
    float ps = 0.f;
    for (int i = tid; i < nposblk; i += MTPB) ps += pos_blk[i];

#pragma unroll
    for (int d = 1; d < 64; d <<= 1) {
        hd += __shfl_xor(hd, d);
        lc += __shfl_xor(lc, d);
        ps += __shfl_xor(ps, d);
        np += __shfl_xor(np, d);
    }
    if ((tid & 63) == 0) {
        int wv = tid >> 6;
        sm[wv] = hd; sm[8 + wv] = lc; sm[16 + wv] = ps;
        cnt[wv] = (unsigned)np;
    }
    __syncthreads();
    if (tid == 0) {
        float thd = 0.f, tlc = 0.f, tps = 0.f; unsigned tnp = 0u;
        for (int wv = 0; wv < MTPB / 64; wv++) {
            thd += sm[wv]; tlc += sm[8 + wv]; tps += sm[16 + wv]; tnp += cnt[wv];
        }
        float n = (float)tnp;
        float conf = (thd + tps) / n;
        float loc = tlc / (n * 4.0f);
        out[0] = conf + loc;
        out[1] = conf;
        out[2] = loc;
    }
}

extern "C" void kernel_launch(void* const* d_in, const int* in_sizes, int n_in,
                              void* d_out, int out_size, void* d_ws, size_t ws_size,
                              hipStream_t stream)
{
    const float* plocs  = (const float*)d_in[0];   // [B,P,4]
    const float* scores = (const float*)d_in[1];   // [B,P,C]
    const float* boxes  = (const float*)d_in[2];   // [B,NOBJ,4] xywh
    const int*   labels = (const int*)d_in[3];     // [B,NOBJ]
    const float* priors = (const float*)d_in[4];   // [P,4] cxcy

    const int P = in_sizes[4] / 4;
    const int B = in_sizes[0] / (P * 4);
    const int C = in_sizes[1] / (B * P);
    const int BP = B * P;

    char* ws = (char*)d_ws;
    float*    loc_seg   = (float*)ws;                         // [B*SEGS]
    int*      n_pos_seg = (int*)(ws + 1024);                  // [B*SEGS]
    float*    hard      = (float*)(ws + 2048);                // [B]
    unsigned* ticket    = (unsigned*)(ws + 3072);             // 1
    unsigned* meta      = (unsigned*)(ws + 4096);             // [BP]
    float*    ce_neg    = (float*)(ws + 4096 + (size_t)BP * 4);        // [BP]
    float*    pos_blk   = (float*)(ws + 4096 + (size_t)BP * 8);        // [CE_BLOCKS]
    char*     ws2       = ws + 4096 + (size_t)BP * 8 + 8192;
    float*    segv      = (float*)ws2;                        // [B*NOBJ*SEGS]
    int*      segp      = (int*)(ws2 + 16384);                // [B*NOBJ*SEGS]
    unsigned char* obj_pack = (unsigned char*)(ws2 + 32768);  // [BP]

    k_match_iou<16><<<B * SEGS, MTPB, 0, stream>>>(boxes, priors, P,
                                                   obj_pack, segv, segp, ticket);

    k_match_fin<16><<<B * SEGS, MTPB, 0, stream>>>(boxes, labels, priors, plocs,
                                                   obj_pack, segv, segp,
                                                   P, meta, n_pos_seg, loc_seg);

    if (C == 91 && (BP & 3) == 0) {
        k_ce91<<<CE_BLOCKS, TPB, 0, stream>>>(scores, meta, BP, ce_neg, pos_blk);
    } else {
        k_ce<<<CE_BLOCKS, TPB, 0, stream>>>(scores, meta, BP, C, ce_neg, pos_blk);
    }

    if (P <= MTPB * 18) {
        k_topk_final<18><<<B, MTPB, 0, stream>>>(ce_neg, n_pos_seg, loc_seg, pos_blk,
                                                 CE_BLOCKS, P, B, hard, ticket,
                                                 (float*)d_out);
    } else {
        k_topk_final<36><<<B, MTPB, 0, stream>>>(ce_neg, n_pos_seg, loc_seg, pos_blk,
                                                 CE_BLOCKS, P, B, hard, ticket,
                                                 (float*)d_out);
    }
}